// Round 1
// baseline (15752.193 us; speedup 1.0000x reference)
//
#include <hip/hip_runtime.h>

#define NWG   256
#define TPB   256
#define Bsz   128
#define Tlen  512
#define Pn    10
#define In    50
#define Hn    512
#define Cn    8
#define KTOT  562          // 512 (h) + 50 (emb)
#define KPAD  564          // padded to 141 float4
#define KC4   141
#define BSL   32           // batch rows per slice
#define JSL   8            // hidden dims per j-slice

#define OFF_H   64                     // floats: barrier counters live in [0..63]
#define HBUF_N  (2*Bsz*Hn)
#define OFF_U   (OFF_H + HBUF_N)
#define UROW    52                     // 50 u + 1 (ba·h) + 1 pad
#define UBUF_N  (3*Bsz*UROW)
#define WS_FLOATS (OFF_U + UBUF_N)

// LDS layout (floats)
#define L_SW    0
#define L_SH    (32*KPAD)
#define L_SWA   (L_SH + 32*KPAD)          // 8*52
#define L_BIAS  (L_SWA + 8*52)            // 32
#define L_GATES (L_BIAS + 32)             // 32*33
#define L_SCORE (L_GATES + 32*33)         // 32*12
#define L_ATTN  (L_SCORE + 32*12)         // 32*12
#define L_HNEW  (L_ATTN + 32*12)          // 32*8
#define LDS_FLOATS (L_HNEW + 32*8)
#define LDS_BYTES  (LDS_FLOATS*4)

__device__ inline void gridBarrier(unsigned* cnt, unsigned* gen, unsigned target) {
  __syncthreads();
  if (threadIdx.x == 0) {
    __threadfence();                       // release: flush my XCD L2 writes
    unsigned old = atomicAdd(cnt, 1u);
    if (old == target * (unsigned)NWG - 1u) {
      __hip_atomic_store(gen, target, __ATOMIC_RELEASE, __HIP_MEMORY_SCOPE_AGENT);
    } else {
      while (__hip_atomic_load(gen, __ATOMIC_RELAXED, __HIP_MEMORY_SCOPE_AGENT) < target) {
        __builtin_amdgcn_s_sleep(2);
      }
    }
    __threadfence();                       // acquire: invalidate stale L1/L2
  }
  __syncthreads();
}

extern "C" __global__ void __launch_bounds__(TPB, 1) fused_att_lstm(
    const float* __restrict__ x,   const float* __restrict__ mask,
    const float* __restrict__ Wa,  const float* __restrict__ ba,
    const float* __restrict__ Wih, const float* __restrict__ Whh,
    const float* __restrict__ bih, const float* __restrict__ bhh,
    const float* __restrict__ Wfc, const float* __restrict__ bfc,
    float* __restrict__ out, float* __restrict__ ws)
{
  extern __shared__ __align__(16) float lds[];
  float* sW     = lds + L_SW;      // [32][KPAD]  rows r=jj*4+g : [W_hh | W_ih | 0,0]
  float* sH     = lds + L_SH;      // [32][KPAD]  [h(512) | emb(50) | 0,0]
  float* sWa    = lds + L_SWA;     // [8][52]     Wa rows of my j-slice, col 50 = ba
  float* sBias  = lds + L_BIAS;    // [32]
  float* sGates = lds + L_GATES;   // [32][33]
  float* sScore = lds + L_SCORE;   // [32][12]
  float* sAttn  = lds + L_ATTN;    // [32][12]
  float* sHnew  = lds + L_HNEW;    // [32][8]

  const int tid = threadIdx.x;
  const int wg  = blockIdx.x;
  const int js  = wg & 63;         // j-slice (8 hidden dims -> 32 gate rows)
  const int bs  = wg >> 6;         // batch slice (32 rows)
  const int bG0 = bs * BSL;
  const int jG0 = js * JSL;

  unsigned* bar_cnt = reinterpret_cast<unsigned*>(ws);
  unsigned* bar_gen = reinterpret_cast<unsigned*>(ws) + 1;
  float* hbuf = ws + OFF_H;        // [2][B][H]
  float* Ubuf = ws + OFF_U;        // [3][B][52]

  // ---- load resident weights into LDS ----
  for (int idx = tid; idx < 32*KPAD; idx += TPB) {
    int r = idx / KPAD, k = idx - r*KPAD;
    int jj = r >> 2, g = r & 3;
    int grow = g*Hn + jG0 + jj;    // torch gate order i,f,g,o
    float v = 0.f;
    if (k < Hn)        v = Whh[grow*Hn + k];
    else if (k < KTOT) v = Wih[grow*In + (k - Hn)];
    sW[idx] = v;
  }
  for (int idx = tid; idx < 8*52; idx += TPB) {
    int jj = idx / 52, i = idx - jj*52;
    float v = 0.f;
    if (i < In)       v = Wa[(jG0+jj)*In + i];
    else if (i == In) v = ba[jG0+jj];
    sWa[idx] = v;
  }
  if (tid < 32) {
    int jj = tid >> 2, g = tid & 3;
    int grow = g*Hn + jG0 + jj;
    sBias[tid] = bih[grow] + bhh[grow];
  }
  if (tid < 32) { sH[tid*KPAD + 562] = 0.f; sH[tid*KPAD + 563] = 0.f; }
  __syncthreads();

  const int lb = tid >> 3, ljj = tid & 7;   // LSTM map: (b, jj)
  const int tx = tid & 15, ty = tid >> 4;   // GEMM map: rows (tx,tx+16), b (ty,ty+16)
  float c_reg = 0.f;
  unsigned bgen = 0;

  for (int t = 0; t < Tlen; ++t) {
    const float* hprev = hbuf + ((t+1)&1)*Bsz*Hn;
    float*       hcur  = hbuf + (t&1)*Bsz*Hn;
    const float* Ucur  = Ubuf + (t%3)*Bsz*UROW;
    float*       Unext = Ubuf + ((t+1)%3)*Bsz*UROW;
    float*       Uzero = Ubuf + ((t+2)%3)*Bsz*UROW;

    // 1. stage h slice (32 x 512) into LDS as float4
    {
      const float4* src  = reinterpret_cast<const float4*>(hprev) + bG0*(Hn/4);
      float4*       dst4 = reinterpret_cast<float4*>(sH);
      #pragma unroll
      for (int it = 0; it < 16; ++it) {
        int f = it*TPB + tid;             // 0..4095
        int b = f >> 7, kf = f & 127;
        dst4[b*KC4 + kf] = src[b*(Hn/4) + kf];
      }
    }
    // 1b. zero my chunk of the buffer accumulated NEXT step (+1 ahead)
    if (tid < 26) Uzero[wg*26 + tid] = 0.f;

    // 2. attention scores for my 32 b's: s = x_t[b,p]·u_b + (ba·h)_b
    for (int idx = tid; idx < BSL*Pn; idx += TPB) {
      int b = idx / Pn, p = idx - b*Pn;
      int bG = bG0 + b;
      const float* xrow = x + (((size_t)bG*Tlen + t)*Pn + p)*In;
      float m = mask[(((size_t)bG*Tlen + t)*Pn + p)*In];
      const float* urow = Ucur + bG*UROW;
      float s = urow[In];
      #pragma unroll
      for (int i = 0; i < In; ++i) s = fmaf(xrow[i], urow[i], s);
      sScore[b*12 + p] = (m > 0.f) ? s : -1e9f;
    }
    __syncthreads();

    // 3. softmax over P=10 (one thread per b)
    if (tid < BSL) {
      int b = tid;
      float mx = -1e30f;
      #pragma unroll
      for (int p = 0; p < Pn; ++p) mx = fmaxf(mx, sScore[b*12+p]);
      float e[Pn]; float den = 0.f;
      #pragma unroll
      for (int p = 0; p < Pn; ++p) { e[p] = expf(sScore[b*12+p] - mx); den += e[p]; }
      float inv = 1.f / den;
      #pragma unroll
      for (int p = 0; p < Pn; ++p) sAttn[b*12+p] = e[p] * inv;
    }
    __syncthreads();

    // 4. emb[b,i] = sum_p attn * x  -> sH[b][512+i]
    for (int idx = tid; idx < BSL*In; idx += TPB) {
      int b = idx / In, i = idx - b*In;
      int bG = bG0 + b;
      const float* xb = x + (((size_t)bG*Tlen + t)*Pn)*In + i;
      float e = 0.f;
      #pragma unroll
      for (int p = 0; p < Pn; ++p) e = fmaf(sAttn[b*12+p], xb[p*In], e);
      sH[b*KPAD + Hn + i] = e;
    }
    __syncthreads();

    // 5. gate GEMM: 32b x 32r, k=564 ; thread tile 2b x 2r
    {
      const float4* hA = reinterpret_cast<const float4*>(sH) + ty*KC4;
      const float4* hB = reinterpret_cast<const float4*>(sH) + (ty+16)*KC4;
      const float4* wA = reinterpret_cast<const float4*>(sW) + tx*KC4;
      const float4* wB = reinterpret_cast<const float4*>(sW) + (tx+16)*KC4;
      float a00a=0,a00b=0,a01a=0,a01b=0,a10a=0,a10b=0,a11a=0,a11b=0;
      #pragma unroll 3
      for (int kc = 0; kc < KC4; ++kc) {
        float4 h0 = hA[kc], h1 = hB[kc], w0 = wA[kc], w1 = wB[kc];
        a00a = fmaf(h0.x, w0.x, a00a); a00b = fmaf(h0.y, w0.y, a00b);
        a00a = fmaf(h0.z, w0.z, a00a); a00b = fmaf(h0.w, w0.w, a00b);
        a01a = fmaf(h0.x, w1.x, a01a); a01b = fmaf(h0.y, w1.y, a01b);
        a01a = fmaf(h0.z, w1.z, a01a); a01b = fmaf(h0.w, w1.w, a01b);
        a10a = fmaf(h1.x, w0.x, a10a); a10b = fmaf(h1.y, w0.y, a10b);
        a10a = fmaf(h1.z, w0.z, a10a); a10b = fmaf(h1.w, w0.w, a10b);
        a11a = fmaf(h1.x, w1.x, a11a); a11b = fmaf(h1.y, w1.y, a11b);
        a11a = fmaf(h1.z, w1.z, a11a); a11b = fmaf(h1.w, w1.w, a11b);
      }
      sGates[ty*33 + tx]           = a00a + a00b + sBias[tx];
      sGates[ty*33 + tx + 16]      = a01a + a01b + sBias[tx+16];
      sGates[(ty+16)*33 + tx]      = a10a + a10b + sBias[tx];
      sGates[(ty+16)*33 + tx + 16] = a11a + a11b + sBias[tx+16];
    }
    __syncthreads();

    // 6. LSTM pointwise; c stays in a register (thread owns (b,jj) forever)
    {
      float gi = sGates[lb*33 + ljj*4 + 0];
      float gf = sGates[lb*33 + ljj*4 + 1];
      float gg = sGates[lb*33 + ljj*4 + 2];
      float go = sGates[lb*33 + ljj*4 + 3];
      float ig = 1.f/(1.f + expf(-gi));
      float fg = 1.f/(1.f + expf(-gf));
      float gc = tanhf(gg);
      float og = 1.f/(1.f + expf(-go));
      c_reg = fg*c_reg + ig*gc;
      float hn = og * tanhf(c_reg);
      hcur[(size_t)(bG0+lb)*Hn + jG0 + ljj] = hn;
      sHnew[lb*8 + ljj] = hn;
    }
    __syncthreads();

    // 7. partial u contributions for NEXT step: u[b,i] += sum_{jj} Wa[j,i]*h_new[b,j]
    for (int idx = tid; idx < BSL*51; idx += TPB) {
      int b = idx / 51, i = idx - b*51;
      float v = 0.f;
      #pragma unroll
      for (int jj = 0; jj < 8; ++jj) v = fmaf(sWa[jj*52 + i], sHnew[b*8 + jj], v);
      atomicAdd(&Unext[(bG0+b)*UROW + i], v);
    }

    // 8. one grid barrier per step
    gridBarrier(bar_cnt, bar_gen, ++bgen);
  }

  // ---- final classifier: logits = h_T @ Wfc^T + bfc (4 WGs, js==0) ----
  if (js == 0) {
    const float* hfin = hbuf + ((Tlen-1)&1)*Bsz*Hn;
    int b = tid >> 3, cc = tid & 7;
    int bG = bG0 + b;
    const float4* hv = reinterpret_cast<const float4*>(hfin + (size_t)bG*Hn);
    const float4* wv = reinterpret_cast<const float4*>(Wfc + cc*Hn);
    float s0=0,s1=0,s2=0,s3=0;
    #pragma unroll 4
    for (int k = 0; k < Hn/4; ++k) {
      float4 a = hv[k], w = wv[k];
      s0 = fmaf(a.x,w.x,s0); s1 = fmaf(a.y,w.y,s1);
      s2 = fmaf(a.z,w.z,s2); s3 = fmaf(a.w,w.w,s3);
    }
    out[bG*Cn + cc] = (s0+s1)+(s2+s3) + bfc[cc];
  }
}

extern "C" void kernel_launch(void* const* d_in, const int* in_sizes, int n_in,
                              void* d_out, int out_size, void* d_ws, size_t ws_size,
                              hipStream_t stream) {
  const float* x    = (const float*)d_in[0];
  const float* mask = (const float*)d_in[1];
  const float* Wa   = (const float*)d_in[2];
  const float* ba   = (const float*)d_in[3];
  const float* Wih  = (const float*)d_in[4];
  const float* Whh  = (const float*)d_in[5];
  const float* bih  = (const float*)d_in[6];
  const float* bhh  = (const float*)d_in[7];
  const float* Wfc  = (const float*)d_in[8];
  const float* bfc  = (const float*)d_in[9];
  float* out = (float*)d_out;
  float* ws  = (float*)d_ws;

  // zero barrier counters + h/u buffers (harness does not re-poison between replays)
  hipMemsetAsync(d_ws, 0, (size_t)WS_FLOATS * sizeof(float), stream);

  (void)hipFuncSetAttribute((const void*)fused_att_lstm,
                            hipFuncAttributeMaxDynamicSharedMemorySize, LDS_BYTES);

  void* args[] = { (void*)&x, (void*)&mask, (void*)&Wa, (void*)&ba,
                   (void*)&Wih, (void*)&Whh, (void*)&bih, (void*)&bhh,
                   (void*)&Wfc, (void*)&bfc, (void*)&out, (void*)&ws };
  hipLaunchCooperativeKernel((void*)fused_att_lstm, dim3(NWG), dim3(TPB),
                             args, LDS_BYTES, stream);
}